// Round 4
// baseline (174.176 us; speedup 1.0000x reference)
//
#include <hip/hip_runtime.h>

// Problem constants
#define B_    256
#define C_    256
#define CH_   128
#define N_    196           // H*W = 14*14
#define NF4   49            // 196 floats = 49 float4 per (b,c) row
#define NROW4 12544         // C_ * NF4 float4 per batch slab
#define EPS   1e-5f

typedef float f32x4 __attribute__((ext_vector_type(4)));   // native vec for NT store

// ---------------------------------------------------------------------------
// K0: W2[c][o] = alpha[o] * sum_k Wz[o,k] * Wv[k,c],
//     alpha[o] = bn_w[o]*rsqrt(bn_var[o]+eps).
// Block per c (grid 256), thread per o (256). Wv column c staged in LDS;
// Wz rows L2-resident (128 KB). Round-0 version measured ~3 us.
// ---------------------------------------------------------------------------
__global__ __launch_bounds__(256) void k_wzvt(const float* __restrict__ Wz,
                                              const float* __restrict__ Wv,
                                              const float* __restrict__ bnw,
                                              const float* __restrict__ bnv,
                                              float* __restrict__ W2) {
    __shared__ float sWv[CH_];
    int c = blockIdx.x;
    int o = threadIdx.x;
    if (o < CH_) sWv[o] = Wv[o * C_ + c];
    __syncthreads();
    const float4* wzrow = (const float4*)(Wz + o * CH_);
    float acc = 0.f;
    #pragma unroll
    for (int k4 = 0; k4 < CH_ / 4; k4++) {
        float4 w = wzrow[k4];
        acc += w.x * sWv[4 * k4 + 0];
        acc += w.y * sWv[4 * k4 + 1];
        acc += w.z * sWv[4 * k4 + 2];
        acc += w.w * sWv[4 * k4 + 3];
    }
    float alpha = bnw[o] * rsqrtf(bnv[o] + EPS);
    W2[c * C_ + o] = acc * alpha;
}

// ---------------------------------------------------------------------------
// K1: ysum[b,c] = sum_n y[b,c,n].  Throughput-shaped: grid 4096 (16 blocks
// per batch), 256 thr. Block covers 16 rows = 784 float4, loaded fully
// coalesced as 3(+1 tail) independent loads/thread; per-float4 partials go
// to LDS (no shuffles on the load path). Reduce: thread (r,j) in 16x16 grid
// sums 3-4 partials of row r, then 4 short shuffle stages (width 16).
// Replaces the 41-us latency-bound k_zs Phase A (6-stage butterflies/row).
// ---------------------------------------------------------------------------
__global__ __launch_bounds__(256) void k_ysum(const float* __restrict__ y,
                                              float* __restrict__ ysum) {
    __shared__ float sP[784];
    int b = blockIdx.x >> 4;          // batch
    int g = blockIdx.x & 15;          // row-group (16 rows)
    int tid = threadIdx.x;

    const float4* base = (const float4*)y + (size_t)b * NROW4 + g * 784;
    #pragma unroll
    for (int k = 0; k < 4; k++) {
        int idx = k * 256 + tid;
        if (idx < 784) {
            float4 v = base[idx];
            sP[idx] = (v.x + v.y) + (v.z + v.w);
        }
    }
    __syncthreads();

    int r = tid >> 4;                 // row within group, 0..15
    int j = tid & 15;                 // slot, 0..15
    const float* row = sP + r * NF4;
    float s = row[j] + row[j + 16] + row[j + 32];
    if (j == 0) s += row[48];
    #pragma unroll
    for (int off = 8; off > 0; off >>= 1)
        s += __shfl_down(s, off, 16);
    if (j == 0) ysum[b * C_ + g * 16 + r] = s;
}

// ---------------------------------------------------------------------------
// K2: Zs[b,o] = sum_c ysum[b,c] * W2[c,o] + (bn_b[o] - bn_m[o]*alpha[o]).
// Block per b, thread per o. ysum row broadcast from LDS; W2 reads coalesced
// and L2-hot (256 KB shared by all blocks). Serial-c dot, unroll 8.
// ---------------------------------------------------------------------------
__global__ __launch_bounds__(256) void k_zmix(const float* __restrict__ ysum,
                                              const float* __restrict__ W2,
                                              const float* __restrict__ bnw,
                                              const float* __restrict__ bnb,
                                              const float* __restrict__ bnm,
                                              const float* __restrict__ bnv,
                                              float* __restrict__ Zs) {
    __shared__ float sY[C_];
    int b = blockIdx.x;
    int o = threadIdx.x;
    sY[o] = ysum[b * C_ + o];
    __syncthreads();
    float acc = 0.f;
    #pragma unroll 8
    for (int c = 0; c < C_; c++)
        acc += sY[c] * W2[c * C_ + o];
    float alpha = bnw[o] * rsqrtf(bnv[o] + EPS);
    Zs[b * C_ + o] = acc + bnb[o] - bnm[o] * alpha;
}

// ---------------------------------------------------------------------------
// K3: out[b,c,n] = x[b,c,n] + Zs[b,c]. float4/thread, coalesced; Zs reads
// are 49-thread broadcasts from L1/L2. NT stores keep the write-once output
// from thrashing L2/L3. Grid 12544 x 256, VGPR-light, streams at HBM BW.
// ---------------------------------------------------------------------------
__global__ __launch_bounds__(256) void k_out(const float* __restrict__ x,
                                             const float* __restrict__ Zs,
                                             float* __restrict__ out) {
    int idx = blockIdx.x * blockDim.x + threadIdx.x;  // float4 index
    int row = idx / NF4;                              // magic-multiply
    float z = Zs[row];
    f32x4 v = ((const f32x4*)x)[idx];
    v.x += z; v.y += z; v.z += z; v.w += z;
    __builtin_nontemporal_store(v, (f32x4*)out + idx);
}

extern "C" void kernel_launch(void* const* d_in, const int* in_sizes, int n_in,
                              void* d_out, int out_size, void* d_ws, size_t ws_size,
                              hipStream_t stream) {
    const float* x   = (const float*)d_in[0];
    const float* y   = (const float*)d_in[1];
    // d_in[2] = Wq, d_in[3] = Wk : dead (softmax over singleton axis == ones)
    const float* Wv  = (const float*)d_in[4];
    const float* Wz  = (const float*)d_in[5];
    const float* bnw = (const float*)d_in[6];
    const float* bnb = (const float*)d_in[7];
    const float* bnm = (const float*)d_in[8];
    const float* bnv = (const float*)d_in[9];
    float* out = (float*)d_out;

    float* ysum = (float*)d_ws;                 // 65536 floats
    float* W2   = ysum + B_ * C_;               // 65536 floats
    float* Zs   = W2 + C_ * C_;                 // 65536 floats

    k_wzvt<<<C_, 256, 0, stream>>>(Wz, Wv, bnw, bnv, W2);
    k_ysum<<<B_ * 16, 256, 0, stream>>>(y, ysum);
    k_zmix<<<B_, 256, 0, stream>>>(ysum, W2, bnw, bnb, bnm, bnv, Zs);
    k_out<<<(B_ * C_ * NF4) / 256, 256, 0, stream>>>(x, Zs, out);
}